// Round 4
// baseline (215.950 us; speedup 1.0000x reference)
//
#include <hip/hip_runtime.h>
#include <hip/hip_cooperative_groups.h>

namespace cg = cooperative_groups;

#define C_CH 64
#define NX 432
#define NY 496
#define NYQ 124                    // NY/4
#define PLANEQ (NX * NYQ)          // float4s per (b,c) plane = 53568

typedef float fx4 __attribute__((ext_vector_type(4)));   // native vector for nontemporal stores

// ---------- fused cooperative path ----------
// Phase 1: init map (B*NX*NY int32) to -1.
// Phase 2: scatter pillar index m into map[s, NX-1-x, y] (flip pre-applied).
// Phase 3: per site-quad (4 consecutive y): 1 int4 map read, then 16 channel-
//          groups of {4 predicated float4 feats gathers, 4x4 register
//          transpose, 4 nontemporal float4 stores (64 lanes x 16B = 1KB)}.
// grid.sync() provides device-scope ordering across XCDs between phases.
__global__ __launch_bounds__(256, 4) void fused_scatter_kernel(
        const float4* __restrict__ feats4,
        const int* __restrict__ bidx,
        const int* __restrict__ sidx,
        int* __restrict__ map,
        float4* __restrict__ out,
        int M, int B) {
    cg::grid_group grid = cg::this_grid();
    const int nthr = gridDim.x * blockDim.x;
    const int tid  = blockIdx.x * blockDim.x + threadIdx.x;

    // phase 1: init map to -1, int4 granularity
    const int mapq = (B * NX * NY) / 4;
    int4* map4 = (int4*)map;
    for (int i = tid; i < mapq; i += nthr)
        map4[i] = make_int4(-1, -1, -1, -1);

    grid.sync();

    // phase 2: scatter pillar indices
    for (int m = tid; m < M; m += nthr) {
        int y = bidx[3 * m + 1];
        int x = bidx[3 * m + 2];
        int s = sidx[m];
        map[s * (NX * NY) + (NX - 1 - x) * NY + y] = m;
    }

    grid.sync();

    // phase 3: gather + transpose + coalesced NT stores
    const int nsq = B * PLANEQ;
    for (int i = tid; i < nsq; i += nthr) {
        int b  = i / PLANEQ;
        int sq = i - b * PLANEQ;
        int4 mm = ((const int4*)map)[i];
        float4* ob = out + (size_t)b * C_CH * PLANEQ + sq;

        #pragma unroll 4
        for (int t = 0; t < 16; ++t) {
            float4 f0 = make_float4(0.f, 0.f, 0.f, 0.f);
            float4 f1 = f0, f2 = f0, f3 = f0;
            if (mm.x >= 0) f0 = feats4[(size_t)mm.x * 16 + t];
            if (mm.y >= 0) f1 = feats4[(size_t)mm.y * 16 + t];
            if (mm.z >= 0) f2 = feats4[(size_t)mm.z * 16 + t];
            if (mm.w >= 0) f3 = feats4[(size_t)mm.w * 16 + t];
            // plane c = t*4 + jj takes component jj of each f
            fx4 o0 = {f0.x, f1.x, f2.x, f3.x};
            fx4 o1 = {f0.y, f1.y, f2.y, f3.y};
            fx4 o2 = {f0.z, f1.z, f2.z, f3.z};
            fx4 o3 = {f0.w, f1.w, f2.w, f3.w};
            fx4* p = (fx4*)(ob + (size_t)(t * 4) * PLANEQ);
            __builtin_nontemporal_store(o0, p);
            __builtin_nontemporal_store(o1, p + PLANEQ);
            __builtin_nontemporal_store(o2, p + 2 * PLANEQ);
            __builtin_nontemporal_store(o3, p + 3 * PLANEQ);
        }
    }
}

// ---------- fallback path (if d_ws too small): zero + direct scatter ----------

__global__ void zero_out_kernel(float4* __restrict__ out, int nq) {
    int i = blockIdx.x * blockDim.x + threadIdx.x;
    if (i < nq) out[i] = make_float4(0.f, 0.f, 0.f, 0.f);
}

__global__ void scatter_feats_kernel(const float* __restrict__ feats,
                                     const int* __restrict__ bidx,
                                     const int* __restrict__ sidx,
                                     float* __restrict__ out, int M) {
    int tid = blockIdx.x * blockDim.x + threadIdx.x;
    if (tid >= M * C_CH) return;
    int m = tid >> 6;
    int c = tid & (C_CH - 1);
    int y = bidx[3 * m + 1];
    int x = bidx[3 * m + 2];
    int s = sidx[m];
    size_t o = (((size_t)s * C_CH + c) * NX + (NX - 1 - x)) * NY + y;
    out[o] = feats[tid];
}

extern "C" void kernel_launch(void* const* d_in, const int* in_sizes, int n_in,
                              void* d_out, int out_size, void* d_ws, size_t ws_size,
                              hipStream_t stream) {
    const float* feats = (const float*)d_in[0];
    const int*   bidx  = (const int*)d_in[1];
    const int*   sidx  = (const int*)d_in[2];
    float*       out   = (float*)d_out;

    int M = in_sizes[0] / C_CH;                     // 48000 pillars total
    int B = out_size / (C_CH * NX * NY);            // 4

    const size_t map_elems = (size_t)B * NX * NY;   // 857,088
    const size_t map_bytes = map_elems * sizeof(int);

    if (ws_size >= map_bytes) {
        int* map = (int*)d_ws;
        const float4* feats4 = (const float4*)feats;
        float4* out4 = (float4*)out;
        void* args[] = {(void*)&feats4, (void*)&bidx, (void*)&sidx,
                        (void*)&map, (void*)&out4, (void*)&M, (void*)&B};
        hipLaunchCooperativeKernel((void*)fused_scatter_kernel,
                                   dim3(1024), dim3(256), args, 0, stream);
    } else {
        int nq = out_size / 4;
        zero_out_kernel<<<(nq + 255) / 256, 256, 0, stream>>>((float4*)out, nq);
        int nt = M * C_CH;
        scatter_feats_kernel<<<(nt + 255) / 256, 256, 0, stream>>>(
            feats, bidx, sidx, out, M);
    }
}

// Round 5
// 53.228 us; speedup vs baseline: 4.0571x; 4.0571x over previous
//
#include <hip/hip_runtime.h>

#define C_CH 64
#define NX 432
#define NY 496
#define NYQ 124                    // NY/4
#define PLANEQ (NX * NYQ)          // float4s per (b,c) plane = 53568

// ---------- fast path: memset(-1) + index scatter + coalesced gather ----------

// Scatter pillar index m into map[s, NX-1-x, y] (flip pre-applied so the
// gather kernel reads the map linearly).
__global__ void scatter_idx_kernel(const int* __restrict__ bidx,
                                   const int* __restrict__ sidx,
                                   int* __restrict__ map, int M) {
    int m = blockIdx.x * blockDim.x + threadIdx.x;
    if (m >= M) return;
    int y = bidx[3 * m + 1];
    int x = bidx[3 * m + 2];
    int s = sidx[m];
    map[(size_t)s * (NX * NY) + (size_t)(NX - 1 - x) * NY + y] = m;
}

// Thread = one site-quad (4 consecutive y) x 8 channel-groups (blockIdx.y
// picks which half of the 16 cg's). Per thread: 1 int4 map load, then per cg:
// up to 4 predicated float4 feats gathers (16B each, every (m,chunk) read
// exactly once grid-wide), 4x4 register transpose, 4 plain float4 stores
// (64 lanes x 16B = 1KB contiguous per instruction, through L2/L3 like the
// 6.9 TB/s fill path).
__global__ void gather_out_kernel(const float4* __restrict__ feats4,
                                  const int4* __restrict__ map,
                                  float4* __restrict__ out, int nsq) {
    int i = blockIdx.x * blockDim.x + threadIdx.x;
    if (i >= nsq) return;
    const int h = blockIdx.y;               // 0/1 -> cg in [8h, 8h+8)
    int b  = i / PLANEQ;
    int sq = i - b * PLANEQ;
    int4 mm = map[i];

    float4* ob = out + ((size_t)b * C_CH + (size_t)h * 32) * PLANEQ + sq;
    const float4* fbase = feats4 + (size_t)h * 8;

    #pragma unroll
    for (int cg = 0; cg < 8; ++cg) {
        float4 f0 = make_float4(0.f, 0.f, 0.f, 0.f);
        float4 f1 = f0, f2 = f0, f3 = f0;
        if (mm.x >= 0) f0 = fbase[(size_t)mm.x * 16 + cg];
        if (mm.y >= 0) f1 = fbase[(size_t)mm.y * 16 + cg];
        if (mm.z >= 0) f2 = fbase[(size_t)mm.z * 16 + cg];
        if (mm.w >= 0) f3 = fbase[(size_t)mm.w * 16 + cg];
        // transpose: plane c = h*32 + cg*4 + jj takes component jj of each f
        float4* p = ob + (size_t)(cg * 4) * PLANEQ;
        p[0]          = make_float4(f0.x, f1.x, f2.x, f3.x);
        p[PLANEQ]     = make_float4(f0.y, f1.y, f2.y, f3.y);
        p[2 * PLANEQ] = make_float4(f0.z, f1.z, f2.z, f3.z);
        p[3 * PLANEQ] = make_float4(f0.w, f1.w, f2.w, f3.w);
    }
}

// ---------- fallback path (if d_ws too small): zero + direct scatter ----------

__global__ void zero_out_kernel(float4* __restrict__ out, int nq) {
    int i = blockIdx.x * blockDim.x + threadIdx.x;
    if (i < nq) out[i] = make_float4(0.f, 0.f, 0.f, 0.f);
}

__global__ void scatter_feats_kernel(const float* __restrict__ feats,
                                     const int* __restrict__ bidx,
                                     const int* __restrict__ sidx,
                                     float* __restrict__ out, int M) {
    int tid = blockIdx.x * blockDim.x + threadIdx.x;
    if (tid >= M * C_CH) return;
    int m = tid >> 6;
    int c = tid & (C_CH - 1);
    int y = bidx[3 * m + 1];
    int x = bidx[3 * m + 2];
    int s = sidx[m];
    size_t o = (((size_t)s * C_CH + c) * NX + (NX - 1 - x)) * NY + y;
    out[o] = feats[tid];
}

extern "C" void kernel_launch(void* const* d_in, const int* in_sizes, int n_in,
                              void* d_out, int out_size, void* d_ws, size_t ws_size,
                              hipStream_t stream) {
    const float* feats = (const float*)d_in[0];
    const int*   bidx  = (const int*)d_in[1];
    const int*   sidx  = (const int*)d_in[2];
    float*       out   = (float*)d_out;

    const int M = in_sizes[0] / C_CH;               // 48000 pillars total
    const int B = out_size / (C_CH * NX * NY);      // 4

    const size_t map_elems = (size_t)B * NX * NY;   // 857,088
    const size_t map_bytes = map_elems * sizeof(int);

    if (ws_size >= map_bytes) {
        int* map = (int*)d_ws;
        // 0xFFFFFFFF == -1 as int32; DMA fill instead of a launch-bound kernel.
        hipMemsetAsync(map, 0xFF, map_bytes, stream);
        scatter_idx_kernel<<<(M + 255) / 256, 256, 0, stream>>>(bidx, sidx, map, M);
        {
            int nsq = B * PLANEQ;                   // 214,272 site-quads
            dim3 grid((nsq + 255) / 256, 2);
            gather_out_kernel<<<grid, 256, 0, stream>>>(
                (const float4*)feats, (const int4*)map, (float4*)out, nsq);
        }
    } else {
        int nq = out_size / 4;
        zero_out_kernel<<<(nq + 255) / 256, 256, 0, stream>>>((float4*)out, nq);
        int nt = M * C_CH;
        scatter_feats_kernel<<<(nt + 255) / 256, 256, 0, stream>>>(
            feats, bidx, sidx, out, M);
    }
}